// Round 2
// baseline (2741.960 us; speedup 1.0000x reference)
//
#include <hip/hip_runtime.h>
#include <stdint.h>

#define BB 4
#define NN 16384
#define NPOINT 1024
#define NSAMPLE 32
#define CC 64
#define RADIUS2 0.00999999977648258209228515625f
#define BIGF 1.0e10f

#define FT 1024  // fps threads per block (16 waves, one CU per batch)

typedef float f32x2 __attribute__((ext_vector_type(2)));

__device__ __forceinline__ f32x2 pk_add(f32x2 a, f32x2 b) {
    f32x2 d;
    asm("v_pk_add_f32 %0, %1, %2" : "=v"(d) : "v"(a), "v"(b));
    return d;
}
__device__ __forceinline__ f32x2 pk_mul(f32x2 a, f32x2 b) {
    f32x2 d;
    asm("v_pk_mul_f32 %0, %1, %2" : "=v"(d) : "v"(a), "v"(b));
    return d;
}

// ---------------- repack w1 (64x67) -> (64x68) padded, pad=0 ----------------
__global__ __launch_bounds__(256) void repack_w1(const float* __restrict__ w1,
                                                 float* __restrict__ w1p) {
    int t = threadIdx.x;
    for (int i = t; i < 64 * 68; i += 256) {
        int o = i / 68, c = i % 68;
        w1p[i] = (c < 67) ? w1[o * 67 + c] : 0.0f;
    }
}

// DPP-based argmax step (max value, min index on ties) — validated bit-exact.
template <int CTRL>
__device__ __forceinline__ void amax_step(float& v, int& i) {
    int nv = __builtin_amdgcn_update_dpp(__float_as_int(v), __float_as_int(v),
                                         CTRL, 0xf, 0xf, false);
    int ni = __builtin_amdgcn_update_dpp(i, i, CTRL, 0xf, 0xf, false);
    float fv = __int_as_float(nv);
    if (fv > v || (fv == v && ni < i)) { v = fv; i = ni; }
}
__device__ __forceinline__ void wave_amax(float& v, int& i) {
    amax_step<0x111>(v, i);  // row_shr:1
    amax_step<0x112>(v, i);  // row_shr:2
    amax_step<0x114>(v, i);  // row_shr:4
    amax_step<0x118>(v, i);  // row_bcast:15
    amax_step<0x142>(v, i);  // row_bcast:15
    amax_step<0x143>(v, i);  // row_bcast:31  -> lane63 holds full wave result
}
// NOTE: the list above must stay exactly shr1,shr2,shr4,shr8,bcast15,bcast31.
#undef AMAX_GUARD

#define PAIR8(X) X(0) X(1) X(2) X(3) X(4) X(5) X(6) X(7)

// ---------------- FPS: one 1024-thread block per batch ----------------
// R0 post-mortem: VGPR_Count=76 at 512thr/16pair proves the coordinate
// arrays were NOT register-resident (need 96+32 regs) -- LLVM rematerialized
// the loads every iteration => ~196KB of L1/L2 re-streaming per iter on one
// CU, 2.12us/iter vs the ~0.4us VALU-issue floor. R1's cross-CU exchange was
// worse (2.27us/iter of store->poll latency + 128-wave spin contention).
// Fix: single block per batch again, but (a) 1024 threads / 8 pairs so the
// pinned footprint fits 4 waves/SIMD, (b) an empty-asm "+v" anchor on every
// coordinate register at the top of the loop body -- the asm "writes" the
// value, so the load result is live across all iterations and CANNOT be
// rematerialized from memory. No __restrict__ on xyz/new_xyz (belt AND
// suspenders vs the remat pathology).
__global__ __launch_bounds__(FT, 4)
void fps_kernel(const float* xyz, float* new_xyz) {
    const int b = blockIdx.x;
    const int t = threadIdx.x;
    const int lane = t & 63;
    const int w = t >> 6;  // 0..15

    __shared__ float2 svi[2][16];  // parity double-buffered per-wave (v, idx)

    const float* xb = xyz + (size_t)b * NN * 3;

#define DECL(k) f32x2 px##k, py##k, pz##k, dd##k;
    PAIR8(DECL)
#undef DECL

    // pair k covers points g = 2*(k*FT + t) and g+1  (g = 2048k + 2t + e)
#define LOAD(k) {                                                   \
        const float* p = xb + (size_t)6 * (k * FT + t);             \
        f32x2 a = *(const f32x2*)(p + 0);                           \
        f32x2 bq = *(const f32x2*)(p + 2);                          \
        f32x2 c = *(const f32x2*)(p + 4);                           \
        px##k.x = a.x;  py##k.x = a.y;  pz##k.x = bq.x;             \
        px##k.y = bq.y; py##k.y = c.x;  pz##k.y = c.y;              \
        dd##k.x = BIGF; dd##k.y = BIGF;                             \
    }
    PAIR8(LOAD)
#undef LOAD

    // initial centroid = point 0
    float cx = xb[0], cy = xb[1], cz = xb[2];

    for (int i = 0; i < NPOINT; ++i) {
        // Register anchor: forces px/py/pz to be in VGPRs here every
        // iteration; kills load rematerialization. Zero instructions.
#define ANCHOR(k) asm volatile("" : "+v"(px##k), "+v"(py##k), "+v"(pz##k));
        PAIR8(ANCHOR)
#undef ANCHOR

        if (t == 0) {
            float* o = new_xyz + ((size_t)b * NPOINT + i) * 3;
            o[0] = cx; o[1] = cy; o[2] = cz;
        }
        if (i == NPOINT - 1) break;  // last centroid written; no next needed

        f32x2 ncx, ncy, ncz;
        ncx.x = -cx; ncx.y = -cx;
        ncy.x = -cy; ncy.y = -cy;
        ncz.x = -cz; ncz.y = -cz;

        float bv = -1.0f;
        int bj = 0;
        // EXACT numpy semantics per element: sub = a+(-b); products rounded
        // individually; sum order (x^2+y^2)+z^2; min; running max with strict
        // > and ascending local slot -> first-occurrence tie-break.
#define STEP(k) {                                                   \
        f32x2 dx = pk_add(px##k, ncx);                              \
        f32x2 dy = pk_add(py##k, ncy);                              \
        f32x2 dz = pk_add(pz##k, ncz);                              \
        f32x2 m0 = pk_mul(dx, dx);                                  \
        f32x2 m1 = pk_mul(dy, dy);                                  \
        f32x2 m2 = pk_mul(dz, dz);                                  \
        f32x2 d  = pk_add(pk_add(m0, m1), m2);                      \
        dd##k.x = fminf(dd##k.x, d.x);                              \
        dd##k.y = fminf(dd##k.y, d.y);                              \
        if (dd##k.x > bv) { bv = dd##k.x; bj = 2 * k; }             \
        if (dd##k.y > bv) { bv = dd##k.y; bj = 2 * k + 1; }         \
    }
        PAIR8(STEP)
#undef STEP
        // global index: g = (bj>>1)*2*FT + 2*t + (bj&1); monotone in bj for
        // fixed t -> in-thread first-occurrence holds
        int bi = (bj >> 1) * (2 * FT) + 2 * t + (bj & 1);

        wave_amax(bv, bi);
        if (lane == 63) svi[i & 1][w] = make_float2(bv, __int_as_float(bi));
        __syncthreads();

        // each lane reads ONE of the 16 wave slots (broadcast groups), then a
        // second wave reduce; duplicates are harmless for (max, min-idx)
        float2 s = svi[i & 1][lane & 15];
        float v2 = s.x;
        int i2 = __float_as_int(s.y);
        wave_amax(v2, i2);
        int ixs = __builtin_amdgcn_readlane(i2, 63);  // uniform -> SGPR

        // load of next centroid (uniform address, L1/L2 resident)
        cx = xb[ixs * 3 + 0];
        cy = xb[ixs * 3 + 1];
        cz = xb[ixs * 3 + 2];
    }
}

// ---------------- ball query: one wave per centroid ----------------
__global__ __launch_bounds__(256) void ballquery_kernel(const float* __restrict__ xyz,
                                                        const float* __restrict__ new_xyz,
                                                        int* __restrict__ nidx) {
    const int t = threadIdx.x;
    const int lane = t & 63;
    const int w = t >> 6;
    const int cid = blockIdx.x * 4 + w;  // 0..4095
    const int b = cid >> 10;

    __shared__ int list[4][NSAMPLE];

    const float* xb = xyz + (size_t)b * NN * 3;
    const float* c = new_xyz + (size_t)cid * 3;
    float cx = c[0], cy = c[1], cz = c[2];

    int cnt = 0;
    for (int base = 0; base < NN && cnt < NSAMPLE; base += 64) {
        int j = base + lane;
        float dx = __fsub_rn(xb[j * 3 + 0], cx);
        float dy = __fsub_rn(xb[j * 3 + 1], cy);
        float dz = __fsub_rn(xb[j * 3 + 2], cz);
        float d2 = __fadd_rn(__fadd_rn(__fmul_rn(dx, dx), __fmul_rn(dy, dy)),
                             __fmul_rn(dz, dz));
        bool hit = d2 < RADIUS2;
        unsigned long long m = __ballot(hit);
        int pre = __popcll(m & ((1ull << lane) - 1ull));
        if (hit) {
            int pos = cnt + pre;
            if (pos < NSAMPLE) list[w][pos] = j;
        }
        cnt += __popcll(m);  // ballot result uniform -> cnt stays wave-uniform
    }
    __syncthreads();
    if (lane < NSAMPLE) {
        int first = list[w][0];  // >=1 hit always: centroid is a member point
        int v = (lane < cnt) ? list[w][lane] : first;
        nidx[(size_t)cid * NSAMPLE + lane] = v;
    }
}

// ---------------- grouped MLP + maxpool: one thread per (point,sample) ------
__global__ __launch_bounds__(256, 2) void mlp_kernel(
    const float* __restrict__ xyz, const float* __restrict__ features,
    const float* __restrict__ new_xyz, const int* __restrict__ nidx,
    const float* __restrict__ w1p, const float* __restrict__ b1,
    const float* __restrict__ w2, const float* __restrict__ b2,
    const float* __restrict__ w3, const float* __restrict__ b3,
    float* __restrict__ out) {
    const int gid = blockIdx.x * 256 + threadIdx.x;
    const int s = gid & 31;
    const int pg = gid >> 5;  // b*1024 + p
    const int b = pg >> 10;
    const int p = pg & 1023;

    const int idx = nidx[gid];
    const float* nc = new_xyz + (size_t)pg * 3;
    const float* pt = xyz + ((size_t)b * NN + idx) * 3;
    float gx = pt[0] - nc[0], gy = pt[1] - nc[1], gz = pt[2] - nc[2];

    float fin[64];
    const float4* fp = (const float4*)(features + ((size_t)b * NN + idx) * CC);
#pragma unroll
    for (int j = 0; j < 16; ++j) {
        float4 q = fp[j];
        fin[4 * j] = q.x; fin[4 * j + 1] = q.y;
        fin[4 * j + 2] = q.z; fin[4 * j + 3] = q.w;
    }

    float h1[64];
#pragma unroll
    for (int o = 0; o < 64; ++o) {
        const float4* wr = (const float4*)(w1p + o * 68);  // uniform -> s_load
        float acc = b1[o];
        float4 q0 = wr[0];
        acc = fmaf(q0.x, gx, acc);
        acc = fmaf(q0.y, gy, acc);
        acc = fmaf(q0.z, gz, acc);
        acc = fmaf(q0.w, fin[0], acc);
#pragma unroll
        for (int j = 1; j < 17; ++j) {
            float4 q = wr[j];
            int c0 = 4 * j - 3;
            acc = fmaf(q.x, fin[c0], acc);
            acc = fmaf(q.y, fin[c0 + 1], acc);
            acc = fmaf(q.z, fin[c0 + 2], acc);
            if (c0 + 3 < 64) acc = fmaf(q.w, fin[c0 + 3], acc);
        }
        h1[o] = fmaxf(acc, 0.0f);
    }

    float h2[64];
#pragma unroll
    for (int o = 0; o < 64; ++o) {
        const float4* wr = (const float4*)(w2 + o * 64);
        float acc = b2[o];
#pragma unroll
        for (int j = 0; j < 16; ++j) {
            float4 q = wr[j];
            acc = fmaf(q.x, h1[4 * j], acc);
            acc = fmaf(q.y, h1[4 * j + 1], acc);
            acc = fmaf(q.z, h1[4 * j + 2], acc);
            acc = fmaf(q.w, h1[4 * j + 3], acc);
        }
        h2[o] = fmaxf(acc, 0.0f);
    }

    float* ob = out + (size_t)b * 128 * NPOINT + p;
#pragma unroll
    for (int o = 0; o < 128; ++o) {
        const float4* wr = (const float4*)(w3 + o * 64);
        float acc = b3[o];
#pragma unroll
        for (int j = 0; j < 16; ++j) {
            float4 q = wr[j];
            acc = fmaf(q.x, h2[4 * j], acc);
            acc = fmaf(q.y, h2[4 * j + 1], acc);
            acc = fmaf(q.z, h2[4 * j + 2], acc);
            acc = fmaf(q.w, h2[4 * j + 3], acc);
        }
        float r = fmaxf(acc, 0.0f);
#pragma unroll
        for (int off = 1; off < 32; off <<= 1) {
            float orr = __shfl_xor(r, off);
            r = fmaxf(r, orr);
        }
        if (s == 0) ob[(size_t)o * NPOINT] = r;
    }
}

extern "C" void kernel_launch(void* const* d_in, const int* in_sizes, int n_in,
                              void* d_out, int out_size, void* d_ws, size_t ws_size,
                              hipStream_t stream) {
    const float* xyz = (const float*)d_in[0];
    const float* features = (const float*)d_in[1];
    const float* w1 = (const float*)d_in[2];
    const float* b1 = (const float*)d_in[3];
    const float* w2 = (const float*)d_in[4];
    const float* b2 = (const float*)d_in[5];
    const float* w3 = (const float*)d_in[6];
    const float* b3 = (const float*)d_in[7];

    float* out = (float*)d_out;
    float* new_xyz = out;                          // B*NPOINT*3
    float* new_feat = out + BB * NPOINT * 3;       // B*128*NPOINT

    int* nidx = (int*)d_ws;                        // B*NPOINT*NSAMPLE ints
    float* w1p = (float*)((char*)d_ws + (size_t)BB * NPOINT * NSAMPLE * sizeof(int));

    hipLaunchKernelGGL(repack_w1, dim3(1), dim3(256), 0, stream, w1, w1p);
    hipLaunchKernelGGL(fps_kernel, dim3(BB), dim3(FT), 0, stream, xyz, new_xyz);
    hipLaunchKernelGGL(ballquery_kernel, dim3(BB * NPOINT / 4), dim3(256), 0, stream,
                       xyz, new_xyz, nidx);
    hipLaunchKernelGGL(mlp_kernel, dim3(BB * NPOINT * NSAMPLE / 256), dim3(256), 0, stream,
                       xyz, features, new_xyz, nidx, w1p, b1, w2, b2, w3, b3, new_feat);
}

// Round 3
// 2717.951 us; speedup vs baseline: 1.0088x; 1.0088x over previous
//
#include <hip/hip_runtime.h>
#include <stdint.h>

#define BB 4
#define NN 16384
#define NPOINT 1024
#define NSAMPLE 32
#define CC 64
#define RADIUS2 0.00999999977648258209228515625f
#define BIGF 1.0e10f

#define FT 1024    // fps threads per block (16 waves, one CU per batch)
#define NPAIR 8    // point-pairs per thread (16 points/thread)

typedef float f32x2 __attribute__((ext_vector_type(2)));

__device__ __forceinline__ f32x2 pk_add(f32x2 a, f32x2 b) {
    f32x2 d;
    asm("v_pk_add_f32 %0, %1, %2" : "=v"(d) : "v"(a), "v"(b));
    return d;
}
__device__ __forceinline__ f32x2 pk_mul(f32x2 a, f32x2 b) {
    f32x2 d;
    asm("v_pk_mul_f32 %0, %1, %2" : "=v"(d) : "v"(a), "v"(b));
    return d;
}

// ---------------- repack w1 (64x67) -> (64x68) padded, pad=0 ----------------
__global__ __launch_bounds__(256) void repack_w1(const float* __restrict__ w1,
                                                 float* __restrict__ w1p) {
    int t = threadIdx.x;
    for (int i = t; i < 64 * 68; i += 256) {
        int o = i / 68, c = i % 68;
        w1p[i] = (c < 67) ? w1[o * 67 + c] : 0.0f;
    }
}

// DPP-based argmax step (max value, min index on ties) — validated bit-exact.
template <int CTRL>
__device__ __forceinline__ void amax_step(float& v, int& i) {
    int nv = __builtin_amdgcn_update_dpp(__float_as_int(v), __float_as_int(v),
                                         CTRL, 0xf, 0xf, false);
    int ni = __builtin_amdgcn_update_dpp(i, i, CTRL, 0xf, 0xf, false);
    float fv = __int_as_float(nv);
    if (fv > v || (fv == v && ni < i)) { v = fv; i = ni; }
}
__device__ __forceinline__ void wave_amax(float& v, int& i) {
    amax_step<0x111>(v, i);  // row_shr:1
    amax_step<0x112>(v, i);  // row_shr:2
    amax_step<0x114>(v, i);  // row_shr:4
    amax_step<0x118>(v, i);  // row_shr:8
    amax_step<0x142>(v, i);  // row_bcast:15
    amax_step<0x143>(v, i);  // row_bcast:31  -> lane63 holds full wave result
}

// ---------------- FPS: one 1024-thread block per batch ----------------
// History: R0 (regs, no anchor) 2.12us/iter -- VGPR=76 proves coords were
// rematerialized from L1/L2 each iter. R1 (32-block exchange) 2.27us/iter --
// cross-XCD store->poll latency dominates. R2 (regs + anchors) 2.30us/iter --
// VGPR=48 == exactly the anchored coord count: allocator pinned coords and
// evicted dd/temps instead. Conclusion: 48+ floats of loop-invariant state in
// VGPRs reliably triggers allocator pathology.
// This version: x,y coordinate planes live in LDS (128 KB -- residency is
// structural, the allocator can't "spill" LDS), z + dd stay in registers
// (32 VGPRs, anchored). Per iter per pair: 2x ds_read_b64 (consecutive 8B per
// lane = 2-way bank alias = free), then the validated pk arithmetic on
// short-lived values. Serial-chain trims: 2nd reduce is 4 DPP steps (lane63's
// row already covers all 16 slots); next-centroid x,y read from LDS instead
// of global. No launch_bounds occupancy arg: 128 KB LDS already pins
// 1 block/CU, letting the compiler derive the 128-VGPR budget.
__global__ __launch_bounds__(FT)
void fps_kernel(const float* xyz, float* new_xyz) {
    const int b = blockIdx.x;
    const int t = threadIdx.x;
    const int lane = t & 63;
    const int w = t >> 6;  // 0..15

    __shared__ float sx[NN];       // 64 KB
    __shared__ float sy[NN];       // 64 KB
    __shared__ float2 svi[2][16];  // parity double-buffered per-wave (v, idx)

    const float* xb = xyz + (size_t)b * NN * 3;

    f32x2 pz[NPAIR];
    f32x2 dd[NPAIR];

    // load + transpose: pair k covers points g = 2*(k*FT+t) and g+1
#pragma unroll
    for (int k = 0; k < NPAIR; ++k) {
        const float* p = xb + (size_t)6 * (k * FT + t);
        f32x2 a = *(const f32x2*)(p + 0);
        f32x2 bq = *(const f32x2*)(p + 2);
        f32x2 c = *(const f32x2*)(p + 4);
        int g = 2 * (k * FT + t);
        f32x2 vx; vx.x = a.x; vx.y = bq.y;
        f32x2 vy; vy.x = a.y; vy.y = c.x;
        *(f32x2*)&sx[g] = vx;      // ds_write_b64, 2-way bank alias (free)
        *(f32x2*)&sy[g] = vy;
        pz[k].x = bq.x; pz[k].y = c.y;
        dd[k].x = BIGF; dd[k].y = BIGF;
    }

    // initial centroid = point 0
    float cx = xb[0], cy = xb[1], cz = xb[2];
    __syncthreads();

    for (int i = 0; i < NPOINT; ++i) {
        // anchor the register-resident state (z coords + running min dists):
        // zero instructions, but the values must be live in VGPRs here ->
        // no remat, no eviction. Only 32 VGPRs pinned.
#pragma unroll
        for (int k = 0; k < NPAIR; ++k)
            asm volatile("" : "+v"(pz[k]), "+v"(dd[k]));

        if (t == 0) {
            float* o = new_xyz + ((size_t)b * NPOINT + i) * 3;
            o[0] = cx; o[1] = cy; o[2] = cz;
        }
        if (i == NPOINT - 1) break;  // last centroid written; no next needed

        f32x2 ncx, ncy, ncz;
        ncx.x = -cx; ncx.y = -cx;
        ncy.x = -cy; ncy.y = -cy;
        ncz.x = -cz; ncz.y = -cz;

        float bv = -1.0f;
        int bj = 0;
        // EXACT numpy semantics per element: sub = a+(-b); products rounded
        // individually; sum order (x^2+y^2)+z^2; min; running max with strict
        // > and ascending local slot -> first-occurrence tie-break.
#pragma unroll
        for (int k = 0; k < NPAIR; ++k) {
            f32x2 vx = *(const f32x2*)&sx[2 * (k * FT + t)];  // ds_read_b64
            f32x2 vy = *(const f32x2*)&sy[2 * (k * FT + t)];
            f32x2 dx = pk_add(vx, ncx);
            f32x2 dy = pk_add(vy, ncy);
            f32x2 dz = pk_add(pz[k], ncz);
            f32x2 m0 = pk_mul(dx, dx);
            f32x2 m1 = pk_mul(dy, dy);
            f32x2 m2 = pk_mul(dz, dz);
            f32x2 d  = pk_add(pk_add(m0, m1), m2);
            dd[k].x = fminf(dd[k].x, d.x);
            dd[k].y = fminf(dd[k].y, d.y);
            if (dd[k].x > bv) { bv = dd[k].x; bj = 2 * k; }
            if (dd[k].y > bv) { bv = dd[k].y; bj = 2 * k + 1; }
        }
        // global index: g = (bj>>1)*2*FT + 2*t + (bj&1); monotone in bj for
        // fixed t -> in-thread first-occurrence holds
        int bi = (bj >> 1) * (2 * FT) + 2 * t + (bj & 1);

        wave_amax(bv, bi);
        if (lane == 63) svi[i & 1][w] = make_float2(bv, __int_as_float(bi));
        __syncthreads();

        // each lane reads ONE of the 16 wave slots; lanes 48..63 cover slots
        // 0..15, so 4 row_shr steps make lane63 the full block reduction —
        // bcast15/bcast31 are unnecessary (we only readlane(63)).
        float2 s = svi[i & 1][lane & 15];
        float v2 = s.x;
        int i2 = __float_as_int(s.y);
        amax_step<0x111>(v2, i2);  // row_shr:1
        amax_step<0x112>(v2, i2);  // row_shr:2
        amax_step<0x114>(v2, i2);  // row_shr:4
        amax_step<0x118>(v2, i2);  // row_shr:8
        int ixs = __builtin_amdgcn_readlane(i2, 63);  // uniform -> SGPR

        // next centroid: x,y from LDS (exact copies), z from global
        cx = sx[ixs];
        cy = sy[ixs];
        cz = xb[ixs * 3 + 2];
    }
}

// ---------------- ball query: one wave per centroid ----------------
__global__ __launch_bounds__(256) void ballquery_kernel(const float* __restrict__ xyz,
                                                        const float* __restrict__ new_xyz,
                                                        int* __restrict__ nidx) {
    const int t = threadIdx.x;
    const int lane = t & 63;
    const int w = t >> 6;
    const int cid = blockIdx.x * 4 + w;  // 0..4095
    const int b = cid >> 10;

    __shared__ int list[4][NSAMPLE];

    const float* xb = xyz + (size_t)b * NN * 3;
    const float* c = new_xyz + (size_t)cid * 3;
    float cx = c[0], cy = c[1], cz = c[2];

    int cnt = 0;
    for (int base = 0; base < NN && cnt < NSAMPLE; base += 64) {
        int j = base + lane;
        float dx = __fsub_rn(xb[j * 3 + 0], cx);
        float dy = __fsub_rn(xb[j * 3 + 1], cy);
        float dz = __fsub_rn(xb[j * 3 + 2], cz);
        float d2 = __fadd_rn(__fadd_rn(__fmul_rn(dx, dx), __fmul_rn(dy, dy)),
                             __fmul_rn(dz, dz));
        bool hit = d2 < RADIUS2;
        unsigned long long m = __ballot(hit);
        int pre = __popcll(m & ((1ull << lane) - 1ull));
        if (hit) {
            int pos = cnt + pre;
            if (pos < NSAMPLE) list[w][pos] = j;
        }
        cnt += __popcll(m);  // ballot result uniform -> cnt stays wave-uniform
    }
    __syncthreads();
    if (lane < NSAMPLE) {
        int first = list[w][0];  // >=1 hit always: centroid is a member point
        int v = (lane < cnt) ? list[w][lane] : first;
        nidx[(size_t)cid * NSAMPLE + lane] = v;
    }
}

// ---------------- grouped MLP + maxpool: one thread per (point,sample) ------
__global__ __launch_bounds__(256, 2) void mlp_kernel(
    const float* __restrict__ xyz, const float* __restrict__ features,
    const float* __restrict__ new_xyz, const int* __restrict__ nidx,
    const float* __restrict__ w1p, const float* __restrict__ b1,
    const float* __restrict__ w2, const float* __restrict__ b2,
    const float* __restrict__ w3, const float* __restrict__ b3,
    float* __restrict__ out) {
    const int gid = blockIdx.x * 256 + threadIdx.x;
    const int s = gid & 31;
    const int pg = gid >> 5;  // b*1024 + p
    const int b = pg >> 10;
    const int p = pg & 1023;

    const int idx = nidx[gid];
    const float* nc = new_xyz + (size_t)pg * 3;
    const float* pt = xyz + ((size_t)b * NN + idx) * 3;
    float gx = pt[0] - nc[0], gy = pt[1] - nc[1], gz = pt[2] - nc[2];

    float fin[64];
    const float4* fp = (const float4*)(features + ((size_t)b * NN + idx) * CC);
#pragma unroll
    for (int j = 0; j < 16; ++j) {
        float4 q = fp[j];
        fin[4 * j] = q.x; fin[4 * j + 1] = q.y;
        fin[4 * j + 2] = q.z; fin[4 * j + 3] = q.w;
    }

    float h1[64];
#pragma unroll
    for (int o = 0; o < 64; ++o) {
        const float4* wr = (const float4*)(w1p + o * 68);  // uniform -> s_load
        float acc = b1[o];
        float4 q0 = wr[0];
        acc = fmaf(q0.x, gx, acc);
        acc = fmaf(q0.y, gy, acc);
        acc = fmaf(q0.z, gz, acc);
        acc = fmaf(q0.w, fin[0], acc);
#pragma unroll
        for (int j = 1; j < 17; ++j) {
            float4 q = wr[j];
            int c0 = 4 * j - 3;
            acc = fmaf(q.x, fin[c0], acc);
            acc = fmaf(q.y, fin[c0 + 1], acc);
            acc = fmaf(q.z, fin[c0 + 2], acc);
            if (c0 + 3 < 64) acc = fmaf(q.w, fin[c0 + 3], acc);
        }
        h1[o] = fmaxf(acc, 0.0f);
    }

    float h2[64];
#pragma unroll
    for (int o = 0; o < 64; ++o) {
        const float4* wr = (const float4*)(w2 + o * 64);
        float acc = b2[o];
#pragma unroll
        for (int j = 0; j < 16; ++j) {
            float4 q = wr[j];
            acc = fmaf(q.x, h1[4 * j], acc);
            acc = fmaf(q.y, h1[4 * j + 1], acc);
            acc = fmaf(q.z, h1[4 * j + 2], acc);
            acc = fmaf(q.w, h1[4 * j + 3], acc);
        }
        h2[o] = fmaxf(acc, 0.0f);
    }

    float* ob = out + (size_t)b * 128 * NPOINT + p;
#pragma unroll
    for (int o = 0; o < 128; ++o) {
        const float4* wr = (const float4*)(w3 + o * 64);
        float acc = b3[o];
#pragma unroll
        for (int j = 0; j < 16; ++j) {
            float4 q = wr[j];
            acc = fmaf(q.x, h2[4 * j], acc);
            acc = fmaf(q.y, h2[4 * j + 1], acc);
            acc = fmaf(q.z, h2[4 * j + 2], acc);
            acc = fmaf(q.w, h2[4 * j + 3], acc);
        }
        float r = fmaxf(acc, 0.0f);
#pragma unroll
        for (int off = 1; off < 32; off <<= 1) {
            float orr = __shfl_xor(r, off);
            r = fmaxf(r, orr);
        }
        if (s == 0) ob[(size_t)o * NPOINT] = r;
    }
}

extern "C" void kernel_launch(void* const* d_in, const int* in_sizes, int n_in,
                              void* d_out, int out_size, void* d_ws, size_t ws_size,
                              hipStream_t stream) {
    const float* xyz = (const float*)d_in[0];
    const float* features = (const float*)d_in[1];
    const float* w1 = (const float*)d_in[2];
    const float* b1 = (const float*)d_in[3];
    const float* w2 = (const float*)d_in[4];
    const float* b2 = (const float*)d_in[5];
    const float* w3 = (const float*)d_in[6];
    const float* b3 = (const float*)d_in[7];

    float* out = (float*)d_out;
    float* new_xyz = out;                          // B*NPOINT*3
    float* new_feat = out + BB * NPOINT * 3;       // B*128*NPOINT

    int* nidx = (int*)d_ws;                        // B*NPOINT*NSAMPLE ints
    float* w1p = (float*)((char*)d_ws + (size_t)BB * NPOINT * NSAMPLE * sizeof(int));

    hipLaunchKernelGGL(repack_w1, dim3(1), dim3(256), 0, stream, w1, w1p);
    hipLaunchKernelGGL(fps_kernel, dim3(BB), dim3(FT), 0, stream, xyz, new_xyz);
    hipLaunchKernelGGL(ballquery_kernel, dim3(BB * NPOINT / 4), dim3(256), 0, stream,
                       xyz, new_xyz, nidx);
    hipLaunchKernelGGL(mlp_kernel, dim3(BB * NPOINT * NSAMPLE / 256), dim3(256), 0, stream,
                       xyz, features, new_xyz, nidx, w1p, b1, w2, b2, w3, b3, new_feat);
}

// Round 4
// 2638.852 us; speedup vs baseline: 1.0391x; 1.0300x over previous
//
#include <hip/hip_runtime.h>
#include <stdint.h>

#define BB 4
#define NN 16384
#define NPOINT 1024
#define NSAMPLE 32
#define CC 64
#define RADIUS2 0.00999999977648258209228515625f
#define BIGF 1.0e10f

#define FT 1024    // fps threads per block (16 waves, one CU per batch)
#define NPAIR 8    // point-pairs per thread (16 points/thread)

typedef float f32x2 __attribute__((ext_vector_type(2)));

__device__ __forceinline__ f32x2 pk_add(f32x2 a, f32x2 b) {
    f32x2 d;
    asm("v_pk_add_f32 %0, %1, %2" : "=v"(d) : "v"(a), "v"(b));
    return d;
}
__device__ __forceinline__ f32x2 pk_mul(f32x2 a, f32x2 b) {
    f32x2 d;
    asm("v_pk_mul_f32 %0, %1, %2" : "=v"(d) : "v"(a), "v"(b));
    return d;
}

// ---------------- repack w1 (64x67) -> (64x68) padded, pad=0 ----------------
__global__ __launch_bounds__(256) void repack_w1(const float* __restrict__ w1,
                                                 float* __restrict__ w1p) {
    int t = threadIdx.x;
    for (int i = t; i < 64 * 68; i += 256) {
        int o = i / 68, c = i % 68;
        w1p[i] = (c < 67) ? w1[o * 67 + c] : 0.0f;
    }
}

// DPP-based argmax step (max value, min index on ties) — validated bit-exact.
template <int CTRL>
__device__ __forceinline__ void amax_step(float& v, int& i) {
    int nv = __builtin_amdgcn_update_dpp(__float_as_int(v), __float_as_int(v),
                                         CTRL, 0xf, 0xf, false);
    int ni = __builtin_amdgcn_update_dpp(i, i, CTRL, 0xf, 0xf, false);
    float fv = __int_as_float(nv);
    if (fv > v || (fv == v && ni < i)) { v = fv; i = ni; }
}
__device__ __forceinline__ void wave_amax(float& v, int& i) {
    amax_step<0x111>(v, i);  // row_shr:1
    amax_step<0x112>(v, i);  // row_shr:2
    amax_step<0x114>(v, i);  // row_shr:4
    amax_step<0x118>(v, i);  // row_shr:8
    amax_step<0x142>(v, i);  // row_bcast:15
    amax_step<0x143>(v, i);  // row_bcast:31  -> lane63 holds full wave result
}

// ---------------- FPS: one 1024-thread block per batch ----------------
// R0-R3 post-mortem: four different residency structures all plateau at
// 2.1-2.3us/iter => coordinate residency was never the limiter. Two costs
// survived every variant:
//  (1) t==0's GLOBAL centroid store right before __syncthreads: the barrier
//      drain (s_waitcnt vmcnt(0)) makes wave0 wait ~0.2us for L2 completion
//      every iteration, and the barrier makes everyone wait on wave0.
//  (2) VGPR=52 in R3 shows the compiler interleaved ds_read->compute per
//      pair (1-2 loads in flight): 8 serial ~120cy LDS latencies per wave
//      per iteration. The per-iteration volatile anchors fenced scheduling.
// R4: (a) centroids stash to LDS, one coalesced global dump after the loop
// (no global store in the loop at all); (b) explicit load-all-then-compute
// split so all 16 ds_read_b64 are in flight together; (c) anchors reduced to
// a ONE-TIME non-volatile "+v" on pz after the initial global load (defines
// the value via asm -> can never be rematerialized; zero loop constraint).
__global__ __launch_bounds__(FT)
void fps_kernel(const float* xyz, float* new_xyz) {
    const int b = blockIdx.x;
    const int t = threadIdx.x;
    const int lane = t & 63;
    const int w = t >> 6;  // 0..15

    __shared__ float sx[NN];          // 64 KB
    __shared__ float sy[NN];          // 64 KB
    __shared__ float st[3 * NPOINT];  // 12 KB centroid stash
    __shared__ float2 svi[2][16];     // parity double-buffered (v, idx)

    const float* xb = xyz + (size_t)b * NN * 3;

    f32x2 pz[NPAIR];
    f32x2 dd[NPAIR];

    // load + transpose: pair k covers points g = 2*(k*FT+t) and g+1
#pragma unroll
    for (int k = 0; k < NPAIR; ++k) {
        const float* p = xb + (size_t)6 * (k * FT + t);
        f32x2 a = *(const f32x2*)(p + 0);
        f32x2 bq = *(const f32x2*)(p + 2);
        f32x2 c = *(const f32x2*)(p + 4);
        int g = 2 * (k * FT + t);
        f32x2 vx; vx.x = a.x; vx.y = bq.y;
        f32x2 vy; vy.x = a.y; vy.y = c.x;
        *(f32x2*)&sx[g] = vx;      // ds_write_b64, 2-way bank alias (free)
        *(f32x2*)&sy[g] = vy;
        pz[k].x = bq.x; pz[k].y = c.y;
        dd[k].x = BIGF; dd[k].y = BIGF;
    }
    // one-time remat-blocker: pz is now defined by the asm, not by a load.
#pragma unroll
    for (int k = 0; k < NPAIR; ++k) asm("" : "+v"(pz[k]));

    // initial centroid = point 0
    float cx = xb[0], cy = xb[1], cz = xb[2];
    __syncthreads();

    for (int i = 0; i < NPOINT; ++i) {
        if (t == 0) {  // stash centroid in LDS; dumped to global after loop
            st[3 * i + 0] = cx; st[3 * i + 1] = cy; st[3 * i + 2] = cz;
        }
        if (i == NPOINT - 1) break;  // last centroid stashed; no next needed

        f32x2 ncx, ncy, ncz;
        ncx.x = -cx; ncx.y = -cx;
        ncy.x = -cy; ncy.y = -cy;
        ncz.x = -cz; ncz.y = -cz;

        // ---- load phase: all 16 ds_read_b64 in flight together ----
        f32x2 vx[NPAIR], vy[NPAIR];
#pragma unroll
        for (int k = 0; k < NPAIR; ++k) {
            vx[k] = *(const f32x2*)&sx[2 * (k * FT + t)];
            vy[k] = *(const f32x2*)&sy[2 * (k * FT + t)];
        }

        // ---- compute phase ----
        float bv = -1.0f;
        int bj = 0;
        // EXACT numpy semantics per element: sub = a+(-b); products rounded
        // individually; sum order (x^2+y^2)+z^2; min; running max with strict
        // > and ascending local slot -> first-occurrence tie-break.
#pragma unroll
        for (int k = 0; k < NPAIR; ++k) {
            f32x2 dx = pk_add(vx[k], ncx);
            f32x2 dy = pk_add(vy[k], ncy);
            f32x2 dz = pk_add(pz[k], ncz);
            f32x2 m0 = pk_mul(dx, dx);
            f32x2 m1 = pk_mul(dy, dy);
            f32x2 m2 = pk_mul(dz, dz);
            f32x2 d  = pk_add(pk_add(m0, m1), m2);
            dd[k].x = fminf(dd[k].x, d.x);
            dd[k].y = fminf(dd[k].y, d.y);
            if (dd[k].x > bv) { bv = dd[k].x; bj = 2 * k; }
            if (dd[k].y > bv) { bv = dd[k].y; bj = 2 * k + 1; }
        }
        // global index: g = (bj>>1)*2*FT + 2*t + (bj&1); monotone in bj for
        // fixed t -> in-thread first-occurrence holds
        int bi = (bj >> 1) * (2 * FT) + 2 * t + (bj & 1);

        wave_amax(bv, bi);
        if (lane == 63) svi[i & 1][w] = make_float2(bv, __int_as_float(bi));
        __syncthreads();

        // each lane reads ONE of the 16 wave slots; lanes 48..63 cover slots
        // 0..15, so 4 row_shr steps make lane63 the full block reduction.
        float2 s = svi[i & 1][lane & 15];
        float v2 = s.x;
        int i2 = __float_as_int(s.y);
        amax_step<0x111>(v2, i2);  // row_shr:1
        amax_step<0x112>(v2, i2);  // row_shr:2
        amax_step<0x114>(v2, i2);  // row_shr:4
        amax_step<0x118>(v2, i2);  // row_shr:8
        int ixs = __builtin_amdgcn_readlane(i2, 63);  // uniform -> SGPR

        // next centroid: x,y from LDS (exact copies), z via scalar load
        cx = sx[ixs];
        cy = sy[ixs];
        cz = xb[ixs * 3 + 2];
    }

    // dump stash -> global, coalesced (3 stores/thread)
    __syncthreads();
    float* ob = new_xyz + (size_t)b * NPOINT * 3;
#pragma unroll
    for (int j = 0; j < 3; ++j) ob[j * FT + t] = st[j * FT + t];
}

// ---------------- ball query: one wave per centroid ----------------
__global__ __launch_bounds__(256) void ballquery_kernel(const float* __restrict__ xyz,
                                                        const float* __restrict__ new_xyz,
                                                        int* __restrict__ nidx) {
    const int t = threadIdx.x;
    const int lane = t & 63;
    const int w = t >> 6;
    const int cid = blockIdx.x * 4 + w;  // 0..4095
    const int b = cid >> 10;

    __shared__ int list[4][NSAMPLE];

    const float* xb = xyz + (size_t)b * NN * 3;
    const float* c = new_xyz + (size_t)cid * 3;
    float cx = c[0], cy = c[1], cz = c[2];

    int cnt = 0;
    for (int base = 0; base < NN && cnt < NSAMPLE; base += 64) {
        int j = base + lane;
        float dx = __fsub_rn(xb[j * 3 + 0], cx);
        float dy = __fsub_rn(xb[j * 3 + 1], cy);
        float dz = __fsub_rn(xb[j * 3 + 2], cz);
        float d2 = __fadd_rn(__fadd_rn(__fmul_rn(dx, dx), __fmul_rn(dy, dy)),
                             __fmul_rn(dz, dz));
        bool hit = d2 < RADIUS2;
        unsigned long long m = __ballot(hit);
        int pre = __popcll(m & ((1ull << lane) - 1ull));
        if (hit) {
            int pos = cnt + pre;
            if (pos < NSAMPLE) list[w][pos] = j;
        }
        cnt += __popcll(m);  // ballot result uniform -> cnt stays wave-uniform
    }
    __syncthreads();
    if (lane < NSAMPLE) {
        int first = list[w][0];  // >=1 hit always: centroid is a member point
        int v = (lane < cnt) ? list[w][lane] : first;
        nidx[(size_t)cid * NSAMPLE + lane] = v;
    }
}

// ---------------- grouped MLP + maxpool: one thread per (point,sample) ------
__global__ __launch_bounds__(256, 2) void mlp_kernel(
    const float* __restrict__ xyz, const float* __restrict__ features,
    const float* __restrict__ new_xyz, const int* __restrict__ nidx,
    const float* __restrict__ w1p, const float* __restrict__ b1,
    const float* __restrict__ w2, const float* __restrict__ b2,
    const float* __restrict__ w3, const float* __restrict__ b3,
    float* __restrict__ out) {
    const int gid = blockIdx.x * 256 + threadIdx.x;
    const int s = gid & 31;
    const int pg = gid >> 5;  // b*1024 + p
    const int b = pg >> 10;
    const int p = pg & 1023;

    const int idx = nidx[gid];
    const float* nc = new_xyz + (size_t)pg * 3;
    const float* pt = xyz + ((size_t)b * NN + idx) * 3;
    float gx = pt[0] - nc[0], gy = pt[1] - nc[1], gz = pt[2] - nc[2];

    float fin[64];
    const float4* fp = (const float4*)(features + ((size_t)b * NN + idx) * CC);
#pragma unroll
    for (int j = 0; j < 16; ++j) {
        float4 q = fp[j];
        fin[4 * j] = q.x; fin[4 * j + 1] = q.y;
        fin[4 * j + 2] = q.z; fin[4 * j + 3] = q.w;
    }

    float h1[64];
#pragma unroll
    for (int o = 0; o < 64; ++o) {
        const float4* wr = (const float4*)(w1p + o * 68);  // uniform -> s_load
        float acc = b1[o];
        float4 q0 = wr[0];
        acc = fmaf(q0.x, gx, acc);
        acc = fmaf(q0.y, gy, acc);
        acc = fmaf(q0.z, gz, acc);
        acc = fmaf(q0.w, fin[0], acc);
#pragma unroll
        for (int j = 1; j < 17; ++j) {
            float4 q = wr[j];
            int c0 = 4 * j - 3;
            acc = fmaf(q.x, fin[c0], acc);
            acc = fmaf(q.y, fin[c0 + 1], acc);
            acc = fmaf(q.z, fin[c0 + 2], acc);
            if (c0 + 3 < 64) acc = fmaf(q.w, fin[c0 + 3], acc);
        }
        h1[o] = fmaxf(acc, 0.0f);
    }

    float h2[64];
#pragma unroll
    for (int o = 0; o < 64; ++o) {
        const float4* wr = (const float4*)(w2 + o * 64);
        float acc = b2[o];
#pragma unroll
        for (int j = 0; j < 16; ++j) {
            float4 q = wr[j];
            acc = fmaf(q.x, h1[4 * j], acc);
            acc = fmaf(q.y, h1[4 * j + 1], acc);
            acc = fmaf(q.z, h1[4 * j + 2], acc);
            acc = fmaf(q.w, h1[4 * j + 3], acc);
        }
        h2[o] = fmaxf(acc, 0.0f);
    }

    float* ob = out + (size_t)b * 128 * NPOINT + p;
#pragma unroll
    for (int o = 0; o < 128; ++o) {
        const float4* wr = (const float4*)(w3 + o * 64);
        float acc = b3[o];
#pragma unroll
        for (int j = 0; j < 16; ++j) {
            float4 q = wr[j];
            acc = fmaf(q.x, h2[4 * j], acc);
            acc = fmaf(q.y, h2[4 * j + 1], acc);
            acc = fmaf(q.z, h2[4 * j + 2], acc);
            acc = fmaf(q.w, h2[4 * j + 3], acc);
        }
        float r = fmaxf(acc, 0.0f);
#pragma unroll
        for (int off = 1; off < 32; off <<= 1) {
            float orr = __shfl_xor(r, off);
            r = fmaxf(r, orr);
        }
        if (s == 0) ob[(size_t)o * NPOINT] = r;
    }
}

extern "C" void kernel_launch(void* const* d_in, const int* in_sizes, int n_in,
                              void* d_out, int out_size, void* d_ws, size_t ws_size,
                              hipStream_t stream) {
    const float* xyz = (const float*)d_in[0];
    const float* features = (const float*)d_in[1];
    const float* w1 = (const float*)d_in[2];
    const float* b1 = (const float*)d_in[3];
    const float* w2 = (const float*)d_in[4];
    const float* b2 = (const float*)d_in[5];
    const float* w3 = (const float*)d_in[6];
    const float* b3 = (const float*)d_in[7];

    float* out = (float*)d_out;
    float* new_xyz = out;                          // B*NPOINT*3
    float* new_feat = out + BB * NPOINT * 3;       // B*128*NPOINT

    int* nidx = (int*)d_ws;                        // B*NPOINT*NSAMPLE ints
    float* w1p = (float*)((char*)d_ws + (size_t)BB * NPOINT * NSAMPLE * sizeof(int));

    hipLaunchKernelGGL(repack_w1, dim3(1), dim3(256), 0, stream, w1, w1p);
    hipLaunchKernelGGL(fps_kernel, dim3(BB), dim3(FT), 0, stream, xyz, new_xyz);
    hipLaunchKernelGGL(ballquery_kernel, dim3(BB * NPOINT / 4), dim3(256), 0, stream,
                       xyz, new_xyz, nidx);
    hipLaunchKernelGGL(mlp_kernel, dim3(BB * NPOINT * NSAMPLE / 256), dim3(256), 0, stream,
                       xyz, features, new_xyz, nidx, w1p, b1, w2, b2, w3, b3, new_feat);
}

// Round 6
// 2534.568 us; speedup vs baseline: 1.0818x; 1.0411x over previous
//
#include <hip/hip_runtime.h>
#include <stdint.h>

#define BB 4
#define NN 16384
#define NPOINT 1024
#define NSAMPLE 32
#define CC 64
#define RADIUS2 0.00999999977648258209228515625f
#define BIGF 1.0e10f

// ---- FPS: 4 slices per batch, 256-thread blocks, reg-resident coords ----
#define FSLICE 4            // blocks per batch
#define FTH 256             // threads per fps block (4 waves, 1 wave/SIMD)
#define FPB (NN / FSLICE)   // 4096 points per block
#define FNP 8               // pairs per thread: FPB / (2*FTH)

typedef float f32x2 __attribute__((ext_vector_type(2)));

__device__ __forceinline__ f32x2 pk_add(f32x2 a, f32x2 b) {
    f32x2 d;
    asm("v_pk_add_f32 %0, %1, %2" : "=v"(d) : "v"(a), "v"(b));
    return d;
}
__device__ __forceinline__ f32x2 pk_mul(f32x2 a, f32x2 b) {
    f32x2 d;
    asm("v_pk_mul_f32 %0, %1, %2" : "=v"(d) : "v"(a), "v"(b));
    return d;
}

// ---------------- repack w1 (64x67) -> (64x68) padded, pad=0 ----------------
// Also zeroes the FPS exchange slots (workspace may be poisoned between runs).
__global__ __launch_bounds__(256) void repack_w1(const float* __restrict__ w1,
                                                 float* __restrict__ w1p,
                                                 unsigned long long* __restrict__ slots) {
    int t = threadIdx.x;
    for (int i = t; i < 64 * 68; i += 256) {
        int o = i / 68, c = i % 68;
        w1p[i] = (c < 67) ? w1[o * 67 + c] : 0.0f;
    }
    slots[t] = 0ull;  // 256 entries (only 32 used)
}

// DPP-based argmax step (max value, min index on ties) — validated bit-exact.
template <int CTRL>
__device__ __forceinline__ void amax_step(float& v, int& i) {
    int nv = __builtin_amdgcn_update_dpp(__float_as_int(v), __float_as_int(v),
                                         CTRL, 0xf, 0xf, false);
    int ni = __builtin_amdgcn_update_dpp(i, i, CTRL, 0xf, 0xf, false);
    float fv = __int_as_float(nv);
    if (fv > v || (fv == v && ni < i)) { v = fv; i = ni; }
}
__device__ __forceinline__ void wave_amax(float& v, int& i) {
    amax_step<0x111>(v, i);  // row_shr:1
    amax_step<0x112>(v, i);  // row_shr:2
    amax_step<0x114>(v, i);  // row_shr:4
    amax_step<0x118>(v, i);  // row_shr:8
    amax_step<0x142>(v, i);  // row_bcast:15
    amax_step<0x143>(v, i);  // row_bcast:31  -> lane63 holds full wave result
}

// ---------------- FPS: 16 blocks (4 per batch), 256 threads each -----------
// R0-R4: every single-CU structure plateaus at 2.1-2.3us/iter (lockstep
// LDS/VALU queueing of 16 barrier-synced waves + 128-VGPR/wave budget).
// R5 (this geometry + coord-payload slots + wave0-only poll) killed the
// container twice -- cause unknown (infra or hang). R6 keeps the geometry but
// downgrades the exchange to EXACTLY the R1 slot protocol that ran to
// completion on this harness (single u64/block: tag|idx|value, relaxed AGENT
// atomics, parity double-buffer), with two hang-proofing mechanisms:
//  - bounded poll (65536 spins ~3ms) + sticky 'dead' flag: a true deadlock
//    becomes a FAST wrong-answer failure with counters, not a container kill.
//    Index extraction is masked &0x3FFF so a timeout can't cause OOB.
//    Blocks always publish even when dead -> no cascading hang.
//  - s_sleep(1) in the spin loop (less fabric pressure).
// Geometry rationale: 1 wave/SIMD + launch_bounds(256,1) => 512-VGPR budget,
// so all 64 coord VGPRs are truly register-resident (first time); per-iter
// compute is ~280cy of pure VALU with no LDS streaming.
__global__ __launch_bounds__(FTH, 1)
void fps_kernel(const float* xyz, float* new_xyz,
                unsigned long long* slots) {
    const int bid = blockIdx.x;
    const int b = bid >> 2;    // batch
    const int kb = bid & 3;    // slice
    const int t = threadIdx.x; // 0..255
    const int lane = t & 63;
    const int w = t >> 6;      // 0..3

    __shared__ float st[3 * NPOINT];  // 12 KB centroid stash (block kb==0)
    __shared__ float2 svi[2][4];      // per-wave candidates (parity dbuf)
    __shared__ float4 bc[2];          // winner coord broadcast (parity dbuf)

    const float* xb = xyz + (size_t)b * NN * 3;
    const int pbase = kb * FPB;

    f32x2 px[FNP], py[FNP], pz[FNP], dd[FNP];

    // load slice: pair k covers local points g = 2*(k*FTH+t) and g+1
#pragma unroll
    for (int k = 0; k < FNP; ++k) {
        const float* p = xb + (size_t)3 * pbase + (size_t)6 * (k * FTH + t);
        f32x2 a = *(const f32x2*)(p + 0);
        f32x2 bq = *(const f32x2*)(p + 2);
        f32x2 c = *(const f32x2*)(p + 4);
        px[k].x = a.x;  py[k].x = a.y;  pz[k].x = bq.x;
        px[k].y = bq.y; py[k].y = c.x;  pz[k].y = c.y;
        dd[k].x = BIGF; dd[k].y = BIGF;
    }
    // one-time remat blocker: coords now defined by asm, not by loads.
#pragma unroll
    for (int k = 0; k < FNP; ++k)
        asm("" : "+v"(px[k]), "+v"(py[k]), "+v"(pz[k]));

    // initial centroid = point 0
    float cx = xb[0], cy = xb[1], cz = xb[2];

    bool dead = false;  // set if a poll ever times out (diagnostic fail-safe)

    for (int i = 0; i < NPOINT; ++i) {
        if (kb == 0 && t == 0) {  // stash; dumped to global after the loop
            st[3 * i + 0] = cx; st[3 * i + 1] = cy; st[3 * i + 2] = cz;
        }
        if (i == NPOINT - 1) break;

        f32x2 ncx, ncy, ncz;
        ncx.x = -cx; ncx.y = -cx;
        ncy.x = -cy; ncy.y = -cy;
        ncz.x = -cz; ncz.y = -cz;

        float bv = -1.0f;
        int bj = 0;
        // EXACT numpy semantics per element: sub = a+(-b); products rounded
        // individually; sum order (x^2+y^2)+z^2; min; running max with strict
        // > and ascending local slot -> first-occurrence tie-break.
#pragma unroll
        for (int k = 0; k < FNP; ++k) {
            f32x2 dx = pk_add(px[k], ncx);
            f32x2 dy = pk_add(py[k], ncy);
            f32x2 dz = pk_add(pz[k], ncz);
            f32x2 m0 = pk_mul(dx, dx);
            f32x2 m1 = pk_mul(dy, dy);
            f32x2 m2 = pk_mul(dz, dz);
            f32x2 d  = pk_add(pk_add(m0, m1), m2);
            dd[k].x = fminf(dd[k].x, d.x);
            dd[k].y = fminf(dd[k].y, d.y);
            if (dd[k].x > bv) { bv = dd[k].x; bj = 2 * k; }
            if (dd[k].y > bv) { bv = dd[k].y; bj = 2 * k + 1; }
        }
        // batch-local index: monotone in bj for fixed t -> first-occurrence
        int bi = pbase + (bj >> 1) * (2 * FTH) + 2 * t + (bj & 1);

        wave_amax(bv, bi);
        if (lane == 63) svi[i & 1][w] = make_float2(bv, __int_as_float(bi));
        __syncthreads();  // barrier A: svi ready

        if (w == 0) {
            // block-level reduce over the 4 wave slots
            float2 sv = svi[i & 1][lane & 3];
            float v2 = sv.x;
            int i2 = __float_as_int(sv.y);
            amax_step<0x111>(v2, i2);  // row_shr:1
            amax_step<0x112>(v2, i2);  // row_shr:2 -> lane3 = block winner
            int s_bi = __builtin_amdgcn_readlane(i2, 3);
            float s_bv = __int_as_float(
                __builtin_amdgcn_readlane(__float_as_int(v2), 3));

            // publish (R1-proven encoding): [ (i+1)<<14 | idx ]<<32 | f32(val)
            const unsigned want = (unsigned)(i + 1);
            unsigned long long* sb = slots + ((size_t)(i & 1) * BB + b) * FSLICE;
            if (lane == 0) {
                unsigned long long sv64 =
                    ((unsigned long long)((want << 14) | (unsigned)s_bi) << 32)
                    | (unsigned long long)__float_as_uint(s_bv);
                __hip_atomic_store(&sb[kb], sv64, __ATOMIC_RELAXED,
                                   __HIP_MEMORY_SCOPE_AGENT);
            }

            // bounded poll: lane l < 4 polls slot l
            unsigned long long s = 0;
            bool ready = (lane >= FSLICE);
            if (!dead) {
                int guard = 0;
                while (true) {
                    if (!ready) {
                        s = __hip_atomic_load(&sb[lane], __ATOMIC_RELAXED,
                                              __HIP_MEMORY_SCOPE_AGENT);
                        ready = ((unsigned)(s >> 46)) == want;
                    }
                    if (__all(ready)) break;
                    if (++guard >= (1 << 16)) { dead = true; break; }
                    __builtin_amdgcn_s_sleep(1);
                }
            }

            // cross-block argmax (max value, min index)
            float rv; int ri;
            if (lane < FSLICE) {
                rv = __uint_as_float((unsigned)s);
                ri = (int)((s >> 32) & 0x3FFFu);  // masked -> never OOB
            } else {
                rv = -1.0f;          // distances >= 0, never wins
                ri = 0x7FFFFFFF;
            }
            amax_step<0x111>(rv, ri);  // row_shr:1
            amax_step<0x112>(rv, ri);  // row_shr:2 -> lane3 = global winner
            int ixs = __builtin_amdgcn_readlane(ri, 3) & (NN - 1);

            if (lane == 0) {
                float4 nc4;
                nc4.x = xb[ixs * 3 + 0];
                nc4.y = xb[ixs * 3 + 1];
                nc4.z = xb[ixs * 3 + 2];
                nc4.w = 0.0f;
                bc[i & 1] = nc4;
            }
        }
        __syncthreads();  // barrier B: winner broadcast ready
        float4 r = bc[i & 1];
        cx = r.x; cy = r.y; cz = r.z;
    }

    // dump stash -> global, coalesced (block kb==0 only)
    if (kb == 0) {
        __syncthreads();
        float* ob = new_xyz + (size_t)b * NPOINT * 3;
        for (int j = t; j < 3 * NPOINT; j += FTH) ob[j] = st[j];
    }
}

// ---------------- ball query: one wave per centroid ----------------
__global__ __launch_bounds__(256) void ballquery_kernel(const float* __restrict__ xyz,
                                                        const float* __restrict__ new_xyz,
                                                        int* __restrict__ nidx) {
    const int t = threadIdx.x;
    const int lane = t & 63;
    const int w = t >> 6;
    const int cid = blockIdx.x * 4 + w;  // 0..4095
    const int b = cid >> 10;

    __shared__ int list[4][NSAMPLE];

    const float* xb = xyz + (size_t)b * NN * 3;
    const float* c = new_xyz + (size_t)cid * 3;
    float cx = c[0], cy = c[1], cz = c[2];

    int cnt = 0;
    for (int base = 0; base < NN && cnt < NSAMPLE; base += 64) {
        int j = base + lane;
        float dx = __fsub_rn(xb[j * 3 + 0], cx);
        float dy = __fsub_rn(xb[j * 3 + 1], cy);
        float dz = __fsub_rn(xb[j * 3 + 2], cz);
        float d2 = __fadd_rn(__fadd_rn(__fmul_rn(dx, dx), __fmul_rn(dy, dy)),
                             __fmul_rn(dz, dz));
        bool hit = d2 < RADIUS2;
        unsigned long long m = __ballot(hit);
        int pre = __popcll(m & ((1ull << lane) - 1ull));
        if (hit) {
            int pos = cnt + pre;
            if (pos < NSAMPLE) list[w][pos] = j;
        }
        cnt += __popcll(m);  // ballot result uniform -> cnt stays wave-uniform
    }
    __syncthreads();
    if (lane < NSAMPLE) {
        int first = list[w][0];  // >=1 hit always: centroid is a member point
        int v = (lane < cnt) ? list[w][lane] : first;
        nidx[(size_t)cid * NSAMPLE + lane] = v;
    }
}

// ---------------- grouped MLP + maxpool: one thread per (point,sample) ------
__global__ __launch_bounds__(256, 2) void mlp_kernel(
    const float* __restrict__ xyz, const float* __restrict__ features,
    const float* __restrict__ new_xyz, const int* __restrict__ nidx,
    const float* __restrict__ w1p, const float* __restrict__ b1,
    const float* __restrict__ w2, const float* __restrict__ b2,
    const float* __restrict__ w3, const float* __restrict__ b3,
    float* __restrict__ out) {
    const int gid = blockIdx.x * 256 + threadIdx.x;
    const int s = gid & 31;
    const int pg = gid >> 5;  // b*1024 + p
    const int b = pg >> 10;
    const int p = pg & 1023;

    const int idx = nidx[gid];
    const float* nc = new_xyz + (size_t)pg * 3;
    const float* pt = xyz + ((size_t)b * NN + idx) * 3;
    float gx = pt[0] - nc[0], gy = pt[1] - nc[1], gz = pt[2] - nc[2];

    float fin[64];
    const float4* fp = (const float4*)(features + ((size_t)b * NN + idx) * CC);
#pragma unroll
    for (int j = 0; j < 16; ++j) {
        float4 q = fp[j];
        fin[4 * j] = q.x; fin[4 * j + 1] = q.y;
        fin[4 * j + 2] = q.z; fin[4 * j + 3] = q.w;
    }

    float h1[64];
#pragma unroll
    for (int o = 0; o < 64; ++o) {
        const float4* wr = (const float4*)(w1p + o * 68);  // uniform -> s_load
        float acc = b1[o];
        float4 q0 = wr[0];
        acc = fmaf(q0.x, gx, acc);
        acc = fmaf(q0.y, gy, acc);
        acc = fmaf(q0.z, gz, acc);
        acc = fmaf(q0.w, fin[0], acc);
#pragma unroll
        for (int j = 1; j < 17; ++j) {
            float4 q = wr[j];
            int c0 = 4 * j - 3;
            acc = fmaf(q.x, fin[c0], acc);
            acc = fmaf(q.y, fin[c0 + 1], acc);
            acc = fmaf(q.z, fin[c0 + 2], acc);
            if (c0 + 3 < 64) acc = fmaf(q.w, fin[c0 + 3], acc);
        }
        h1[o] = fmaxf(acc, 0.0f);
    }

    float h2[64];
#pragma unroll
    for (int o = 0; o < 64; ++o) {
        const float4* wr = (const float4*)(w2 + o * 64);
        float acc = b2[o];
#pragma unroll
        for (int j = 0; j < 16; ++j) {
            float4 q = wr[j];
            acc = fmaf(q.x, h1[4 * j], acc);
            acc = fmaf(q.y, h1[4 * j + 1], acc);
            acc = fmaf(q.z, h1[4 * j + 2], acc);
            acc = fmaf(q.w, h1[4 * j + 3], acc);
        }
        h2[o] = fmaxf(acc, 0.0f);
    }

    float* ob = out + (size_t)b * 128 * NPOINT + p;
#pragma unroll
    for (int o = 0; o < 128; ++o) {
        const float4* wr = (const float4*)(w3 + o * 64);
        float acc = b3[o];
#pragma unroll
        for (int j = 0; j < 16; ++j) {
            float4 q = wr[j];
            acc = fmaf(q.x, h2[4 * j], acc);
            acc = fmaf(q.y, h2[4 * j + 1], acc);
            acc = fmaf(q.z, h2[4 * j + 2], acc);
            acc = fmaf(q.w, h2[4 * j + 3], acc);
        }
        float r = fmaxf(acc, 0.0f);
#pragma unroll
        for (int off = 1; off < 32; off <<= 1) {
            float orr = __shfl_xor(r, off);
            r = fmaxf(r, orr);
        }
        if (s == 0) ob[(size_t)o * NPOINT] = r;
    }
}

extern "C" void kernel_launch(void* const* d_in, const int* in_sizes, int n_in,
                              void* d_out, int out_size, void* d_ws, size_t ws_size,
                              hipStream_t stream) {
    const float* xyz = (const float*)d_in[0];
    const float* features = (const float*)d_in[1];
    const float* w1 = (const float*)d_in[2];
    const float* b1 = (const float*)d_in[3];
    const float* w2 = (const float*)d_in[4];
    const float* b2 = (const float*)d_in[5];
    const float* w3 = (const float*)d_in[6];
    const float* b3 = (const float*)d_in[7];

    float* out = (float*)d_out;
    float* new_xyz = out;                          // B*NPOINT*3
    float* new_feat = out + BB * NPOINT * 3;       // B*128*NPOINT

    int* nidx = (int*)d_ws;                        // B*NPOINT*NSAMPLE ints
    float* w1p = (float*)((char*)d_ws + (size_t)BB * NPOINT * NSAMPLE * sizeof(int));
    unsigned long long* slots = (unsigned long long*)((char*)d_ws
                                + (size_t)BB * NPOINT * NSAMPLE * sizeof(int)
                                + (size_t)64 * 68 * sizeof(float));  // 8B-aligned

    hipLaunchKernelGGL(repack_w1, dim3(1), dim3(256), 0, stream, w1, w1p, slots);
    hipLaunchKernelGGL(fps_kernel, dim3(BB * FSLICE), dim3(FTH), 0, stream,
                       xyz, new_xyz, slots);
    hipLaunchKernelGGL(ballquery_kernel, dim3(BB * NPOINT / 4), dim3(256), 0, stream,
                       xyz, new_xyz, nidx);
    hipLaunchKernelGGL(mlp_kernel, dim3(BB * NPOINT * NSAMPLE / 256), dim3(256), 0, stream,
                       xyz, features, new_xyz, nidx, w1p, b1, w2, b2, w3, b3, new_feat);
}